// Round 21
// baseline (295.015 us; speedup 1.0000x reference)
//
#include <hip/hip_runtime.h>
#include <hip/hip_fp16.h>
#include <cstdint>
#include <cstddef>

// ---- problem constants ----
#define SEQ 2048
#define DM 1024
#define NH 16
#define NB 20

typedef _Float16 half8 __attribute__((ext_vector_type(8)));
typedef _Float16 half4 __attribute__((ext_vector_type(4)));
typedef _Float16 h2v __attribute__((ext_vector_type(2)));
typedef float f32x4 __attribute__((ext_vector_type(4)));
typedef float f32x2 __attribute__((ext_vector_type(2)));
typedef int i32x4 __attribute__((ext_vector_type(4)));
typedef unsigned int u32;
typedef unsigned int u32x2 __attribute__((ext_vector_type(2)));

// ws layout (25,165,824 B total):
//  KF [2][16][64][2048] halves : per (b,h,kt): [k2][dh][lane][8]       (QK^T A-frags, 16x16x32)
//  VF [2][16][64][2048] halves : per (b,h,kt): [dt][lane][k2*4+r]      (PV B-frags, K=32 pi-order)
//  PB [2][64][65536] bytes     : per (b,qblk32): [kt][lane][qs][k2] u32 = pair01 | pair23<<16
//                                pair = bucket0*21+bucket1 (bucket 20 = masked sentinel)
#define KF_HALVES 4194304
#define VF_HALVES 4194304

// =================== prepass (identical to R17) ===================
__global__ __launch_bounds__(256) void pa_prep(
    const float* __restrict__ v, const float* __restrict__ k,
    const int* __restrict__ diff, const int* __restrict__ mask,
    _Float16* __restrict__ KF, _Float16* __restrict__ VF,
    unsigned char* __restrict__ PB) {
  const int bid = blockIdx.x, tid = threadIdx.x;
  if (bid < 2048) {
    int img = bid >> 4;                    // 0..127 = b*64+kt
    int bb = img >> 6, kt = img & 63;
    int tix = ((bid & 15) << 8) | tid;     // 0..4095
    int r = tix >> 7;                      // row in tile 0..31 (= k2*16+l16)
    int c0 = (tix & 127) << 3;             // col 0..1016
    const float* src = k + ((size_t)(bb * SEQ + kt * 32 + r)) * DM + c0;
    f32x4 a = *(const f32x4*)src;
    f32x4 c = *(const f32x4*)(src + 4);
    half8 o = {(_Float16)a[0], (_Float16)a[1], (_Float16)a[2], (_Float16)a[3],
               (_Float16)c[0], (_Float16)c[1], (_Float16)c[2], (_Float16)c[3]};
    int h = c0 >> 6, dh = (c0 >> 5) & 1, g4 = (c0 >> 3) & 3;
    int k2 = r >> 4, l16 = r & 15;
    int lane = g4 * 16 + l16;
    size_t off = ((size_t)((bb * 16 + h) * 64 + kt)) * 2048 + (k2 * 2 + dh) * 512 + lane * 8;
    *(half8*)(KF + off) = o;
  } else if (bid < 3072) {
    int b3 = bid - 2048;
    int img = b3 >> 3;                     // 0..127
    int bb = img >> 6, kt = img & 63;
    int tix = ((b3 & 7) << 8) | tid;       // 0..2047
    int kq = tix >> 8;                     // 0..7
    int k2 = kq >> 2, g4 = kq & 3;
    int d0 = (tix & 255) << 2;             // 0..1020
    const float* src = v + ((size_t)(bb * SEQ + kt * 32 + k2 * 16 + g4 * 4)) * DM + d0;
    f32x4 m0 = *(const f32x4*)(src);
    f32x4 m1 = *(const f32x4*)(src + DM);
    f32x4 m2 = *(const f32x4*)(src + 2 * DM);
    f32x4 m3 = *(const f32x4*)(src + 3 * DM);
#pragma unroll
    for (int i = 0; i < 4; ++i) {
      int d = d0 + i;
      int l16 = d & 15, dt = (d >> 4) & 3, h = d >> 6;
      int lane = g4 * 16 + l16;
      half4 o = {(_Float16)m0[i], (_Float16)m1[i], (_Float16)m2[i], (_Float16)m3[i]};
      size_t off = ((size_t)((bb * 16 + h) * 64 + kt)) * 2048 + dt * 512 + lane * 8 + k2 * 4;
      *(half4*)(VF + off) = o;
    }
  } else {
    int b4 = bid - 3072;                   // 0..4095
    int job = b4 >> 5;                     // 0..127 = b*64+qblk32
    int bb = job >> 6, qblk = job & 63;
    int tix = ((b4 & 31) << 8) | tid;      // 0..8191
    int kt = tix >> 7;
    int rem = tix & 127;
    int g4 = rem & 3, l16 = (rem >> 2) & 15, qs = rem >> 6;
    int lane = g4 * 16 + l16;
    int qrow = qblk * 32 + qs * 16 + l16;
    size_t rowbase = ((size_t)(bb * SEQ + qrow)) * SEQ;
    u32x2 wds;
#pragma unroll
    for (int k2 = 0; k2 < 2; ++k2) {
      int kk = kt * 32 + k2 * 16 + g4 * 4;
      i32x4 dv = *(const i32x4*)(diff + rowbase + kk);
      i32x4 mv = *(const i32x4*)(mask + rowbase + kk);
      u32 bk[4];
#pragma unroll
      for (int r = 0; r < 4; ++r) bk[r] = mv[r] ? (u32)dv[r] : 20u;  // 20 = masked sentinel
      u32 pi01 = bk[0] * 21 + bk[1];
      u32 pi23 = bk[2] * 21 + bk[3];
      wds[k2] = pi01 | (pi23 << 16);
    }
    size_t off = ((size_t)job) * 65536 + (size_t)kt * 1024 + (size_t)lane * 16 + (size_t)qs * 8;
    *(u32x2*)(PB + off) = wds;
  }
}

__device__ __forceinline__ void gll16(const _Float16* g, _Float16* l) {
  __builtin_amdgcn_global_load_lds(
      (const __attribute__((address_space(1))) unsigned int*)g,
      (__attribute__((address_space(3))) unsigned int*)l, 16, 0, 0);
}

// packed-f16 silu; bias already in s (came through the MFMA C-operand in f32)
__device__ __forceinline__ half4 silu4nb(const f32x4& s) {
  h2v x01 = __builtin_bit_cast(h2v, __builtin_amdgcn_cvt_pkrtz(s[0], s[1]));
  h2v x23 = __builtin_bit_cast(h2v, __builtin_amdgcn_cvt_pkrtz(s[2], s[3]));
  const h2v NL2E = {(_Float16)-1.44269504f, (_Float16)-1.44269504f};
  const h2v ONE = {(_Float16)1.0f, (_Float16)1.0f};
  h2v m01 = x01 * NL2E, m23 = x23 * NL2E;
  h2v e01 = __builtin_bit_cast(h2v, h2exp2(__builtin_bit_cast(__half2, m01)));
  h2v e23 = __builtin_bit_cast(h2v, h2exp2(__builtin_bit_cast(__half2, m23)));
  h2v d01 = e01 + ONE, d23 = e23 + ONE;
  h2v y01 = x01 * __builtin_bit_cast(h2v, h2rcp(__builtin_bit_cast(__half2, d01)));
  h2v y23 = x23 * __builtin_bit_cast(h2v, h2rcp(__builtin_bit_cast(__half2, d23)));
  return (half4){y01[0], y01[1], y23[0], y23[1]};
}

struct BiasSet { f32x4 b[2][2]; };  // [qs][k2], f32 — feeds QK C-operand

// =================== main: 8 waves/SIMD (hardware max TLP) ===================
// R20: TLP 2->4 waves/SIMD = -3.5%. Extend once more: 1024 blocks x 512 thr = 4 blocks/CU
// x 8 waves = 32 waves/CU (max). Block = 2 qblks x 4 k-quarters (16 tiles each); 8-slot
// K-ring (quarter q alternates slots q,q+4: stage(T+4) fills the slot freed by last
// phase's barrier, compute covers latency; 16 barriers). V VMEM-direct; 4-way k-reduce
// in ring scratch. VGPR gate: (512,8) caps at 64; R20 used 52.
__global__ __launch_bounds__(512, 8) void pa_main(
    const _Float16* __restrict__ KF, const _Float16* __restrict__ VF,
    const unsigned char* __restrict__ PB, const float* __restrict__ q,
    const float* __restrict__ relbias, float* __restrict__ out) {
  __shared__ __align__(16) _Float16 ringK[8][2048];  // 32KB K ring (+ reduce scratch)
  __shared__ f32x2 tabF[441];                        // (rb[i], rb[j]) pair table

  const int tid = threadIdx.x, lane = tid & 63, wid = tid >> 6;  // wid 0..7
  const int qt = wid & 3, w2 = wid >> 2;   // k-quarter, qblk-within-block
  const int l16 = lane & 15, g4 = lane >> 4;
  const int xcd = blockIdx.x & 7;          // bid%8 = XCD
  const int i = blockIdx.x >> 3;           // 0..127 within XCD
  const int b = xcd >> 2;                  // XCD owns (b, 4-head group)
  const int hg = xcd & 3;
  const int h = hg * 4 + (i & 3);
  const int qgrp2 = i >> 2;                // 0..31
  const int qblk = qgrp2 * 2 + w2;         // 0..63
  const int qbase = qblk * 32;

  // build pair table
  for (int e = tid; e < 441; e += 512) {
    int bi = e / 21, bj = e - bi * 21;
    float vi = (bi < NB) ? relbias[bi * NH + h] : -30000.0f;
    float vj = (bj < NB) ? relbias[bj * NH + h] : -30000.0f;
    tabF[e] = (f32x2){vi, vj};
  }

  half8 qf[2][2];
#pragma unroll
  for (int qs = 0; qs < 2; ++qs)
#pragma unroll
    for (int dh = 0; dh < 2; ++dh) {
      const float* s = q + ((size_t)(b * SEQ + qbase + qs * 16 + l16)) * DM + h * 64 + dh * 32 + g4 * 8;
      f32x4 a = *(const f32x4*)s;
      f32x4 c = *(const f32x4*)(s + 4);
      qf[qs][dh] = {(_Float16)(a[0] * 0.125f), (_Float16)(a[1] * 0.125f),
                    (_Float16)(a[2] * 0.125f), (_Float16)(a[3] * 0.125f),
                    (_Float16)(c[0] * 0.125f), (_Float16)(c[1] * 0.125f),
                    (_Float16)(c[2] * 0.125f), (_Float16)(c[3] * 0.125f)};
    }

  f32x4 acc[2][4];
#pragma unroll
  for (int qs = 0; qs < 2; ++qs)
#pragma unroll
    for (int dt = 0; dt < 4; ++dt) acc[qs][dt] = (f32x4){0.f, 0.f, 0.f, 0.f};

  const _Float16* kfb = KF + ((size_t)((b * 16 + h) * 64)) * 2048 + lane * 8;
  const _Float16* vfb = VF + ((size_t)((b * 16 + h) * 64)) * 2048 + lane * 8;
  const unsigned char* pbb = PB + ((size_t)(b * 64 + qblk)) * 65536 + lane * 16;
  const int ch = w2 * 1024;                // this wave's half-tile chunk

  // quarter's 2 waves stage the tile's two 2KB halves (2 gll16 each)
#define STAGE(T)                                                            \
  do {                                                                      \
    gll16(kfb + (size_t)(T) * 2048 + ch, &ringK[(T) & 7][ch]);              \
    gll16(kfb + (size_t)(T) * 2048 + ch + 512, &ringK[(T) & 7][ch + 512]);  \
  } while (0)
#define CLMP(T) ((T) < 64 ? (T) : 63)

#define GATHER(BS, PQ)                                                 \
  do {                                                                 \
    _Pragma("unroll") for (int qs = 0; qs < 2; ++qs)                   \
      _Pragma("unroll") for (int k2 = 0; k2 < 2; ++k2) {               \
        u32 w = (u32)PQ[qs * 2 + k2];                                  \
        f32x2 p01 = tabF[w & 0xffffu];                                 \
        f32x2 p23 = tabF[w >> 16];                                     \
        BS.b[qs][k2] = (f32x4){p01[0], p01[1], p23[0], p23[1]};        \
      }                                                                \
  } while (0)

#define COMPUTE(T, BS)                                                                       \
  do {                                                                                       \
    int sl_ = (T) & 7;                                                                       \
    half8 vvr[4];                                                                            \
    _Pragma("unroll") for (int j = 0; j < 4; ++j)                                            \
      vvr[j] = *(const half8*)(vfb + (size_t)(T) * 2048 + j * 512);   /* VMEM / L1 */        \
    half8 kfr[4];                                                                            \
    _Pragma("unroll") for (int j = 0; j < 4; ++j)                                            \
      kfr[j] = *(const half8*)&ringK[sl_][j * 512 + lane * 8];        /* LDS pipe */         \
    f32x4 sa[2][2];                                                                          \
    _Pragma("unroll") for (int qs = 0; qs < 2; ++qs)                                         \
      _Pragma("unroll") for (int k2 = 0; k2 < 2; ++k2) {                                     \
        sa[qs][k2] = __builtin_amdgcn_mfma_f32_16x16x32_f16(kfr[k2 * 2 + 0], qf[qs][0],      \
                                                            BS.b[qs][k2], 0, 0, 0);          \
        sa[qs][k2] = __builtin_amdgcn_mfma_f32_16x16x32_f16(kfr[k2 * 2 + 1], qf[qs][1],      \
                                                            sa[qs][k2], 0, 0, 0);            \
      }                                                                                      \
    half8 pf8[2];                                                                            \
    _Pragma("unroll") for (int qs = 0; qs < 2; ++qs) {                                       \
      half4 p0 = silu4nb(sa[qs][0]);                                                         \
      half4 p1 = silu4nb(sa[qs][1]);                                                         \
      pf8[qs] = (half8){p0[0], p0[1], p0[2], p0[3], p1[0], p1[1], p1[2], p1[3]};             \
    }                                                                                        \
    _Pragma("unroll") for (int qs = 0; qs < 2; ++qs)                                         \
      _Pragma("unroll") for (int dt = 0; dt < 4; ++dt)                                       \
        acc[qs][dt] = __builtin_amdgcn_mfma_f32_16x16x32_f16(pf8[qs], vvr[dt],               \
                                                             acc[qs][dt], 0, 0, 0);          \
  } while (0)

  BiasSet bias;
  i32x4 pqCur, pqNext;

  // prologue: stage tile qt (slot qt); pq(qt) in flight
  STAGE(qt);
  pqCur = *(const i32x4*)(pbb + (size_t)qt * 1024);
  __syncthreads();                       // slots 0..3 staged

  for (int p = 0; p < 16; ++p) {
    const int T = 4 * p + qt;
    // stage T+4 into slot (T+4)&7 — freed by last phase's barrier
    if (T + 4 < 64) STAGE(T + 4);
    pqNext = *(const i32x4*)(pbb + (size_t)CLMP(T + 4) * 1024);
    __builtin_amdgcn_sched_barrier(0);
    GATHER(bias, pqCur);
    COMPUTE(T, bias);                    // covers stage(T+4) latency
    __syncthreads();                     // stage complete; slot (T)&7 released
    pqCur = pqNext;
  }
#undef STAGE
#undef CLMP
#undef GATHER
#undef COMPUTE

  // epilogue: 4-way k-quarter reduce via ring scratch (2 rounds), quarter 0 stores
  f32x4* red = (f32x4*)ringK;            // 2048 f32x4 = 32KB
#pragma unroll
  for (int qs = 0; qs < 2; ++qs) {
    __syncthreads();
    if (qt > 0) {
#pragma unroll
      for (int dt = 0; dt < 4; ++dt)
        red[((qt - 1) * 2 + w2) * 256 + lane * 4 + dt] = acc[qs][dt];
    }
    __syncthreads();
    if (qt == 0) {
#pragma unroll
      for (int dt = 0; dt < 4; ++dt) {
        f32x4 sum = acc[qs][dt];
#pragma unroll
        for (int qq = 1; qq < 4; ++qq)
          sum += red[((qq - 1) * 2 + w2) * 256 + lane * 4 + dt];
#pragma unroll
        for (int r = 0; r < 4; ++r) {
          int qrow = qbase + qs * 16 + g4 * 4 + r;
          int d = h * 64 + dt * 16 + l16;
          out[((size_t)(b * SEQ) + qrow) * DM + d] = sum[r];
        }
      }
    }
  }
}

extern "C" void kernel_launch(void* const* d_in, const int* in_sizes, int n_in,
                              void* d_out, int out_size, void* d_ws, size_t ws_size,
                              hipStream_t stream) {
  const float* v = (const float*)d_in[0];
  const float* k = (const float*)d_in[1];
  const float* q = (const float*)d_in[2];
  const int* mask = (const int*)d_in[3];
  const int* diff = (const int*)d_in[4];
  const float* relbias = (const float*)d_in[5];
  float* out = (float*)d_out;

  _Float16* KF = (_Float16*)d_ws;
  _Float16* VF = KF + KF_HALVES;
  unsigned char* PB = (unsigned char*)(VF + VF_HALVES);
  if (ws_size < (size_t)25165824) return;

  pa_prep<<<7168, 256, 0, stream>>>(v, k, diff, mask, KF, VF, PB);
  pa_main<<<1024, 512, 0, stream>>>(KF, VF, PB, q, relbias, out);
}

// Round 22
// 94.473 us; speedup vs baseline: 3.1227x; 3.1227x over previous
//
#include <hip/hip_runtime.h>
#include <hip/hip_fp16.h>
#include <cstdint>
#include <cstddef>

// ---- problem constants ----
#define SEQ 2048
#define DM 1024
#define NH 16
#define NB 20

typedef _Float16 half8 __attribute__((ext_vector_type(8)));
typedef _Float16 half4 __attribute__((ext_vector_type(4)));
typedef _Float16 h2v __attribute__((ext_vector_type(2)));
typedef float f32x4 __attribute__((ext_vector_type(4)));
typedef float f32x2 __attribute__((ext_vector_type(2)));
typedef int i32x4 __attribute__((ext_vector_type(4)));
typedef unsigned int u32;
typedef unsigned int u32x2 __attribute__((ext_vector_type(2)));

// ws layout (25,165,824 B total):
//  KF [2][16][64][2048] halves : per (b,h,kt): [k2][dh][lane][8]       (QK^T A-frags, 16x16x32)
//  VF [2][16][64][2048] halves : per (b,h,kt): [dt][lane][k2*4+r]      (PV B-frags, K=32 pi-order)
//  PB [2][64][65536] bytes     : per (b,qblk32): [kt][lane][qs][k2] u32 = pair01 | pair23<<16
//                                pair = bucket0*21+bucket1 (bucket 20 = masked sentinel)
#define KF_HALVES 4194304
#define VF_HALVES 4194304

// =================== prepass (identical to R17) ===================
__global__ __launch_bounds__(256) void pa_prep(
    const float* __restrict__ v, const float* __restrict__ k,
    const int* __restrict__ diff, const int* __restrict__ mask,
    _Float16* __restrict__ KF, _Float16* __restrict__ VF,
    unsigned char* __restrict__ PB) {
  const int bid = blockIdx.x, tid = threadIdx.x;
  if (bid < 2048) {
    int img = bid >> 4;                    // 0..127 = b*64+kt
    int bb = img >> 6, kt = img & 63;
    int tix = ((bid & 15) << 8) | tid;     // 0..4095
    int r = tix >> 7;                      // row in tile 0..31 (= k2*16+l16)
    int c0 = (tix & 127) << 3;             // col 0..1016
    const float* src = k + ((size_t)(bb * SEQ + kt * 32 + r)) * DM + c0;
    f32x4 a = *(const f32x4*)src;
    f32x4 c = *(const f32x4*)(src + 4);
    half8 o = {(_Float16)a[0], (_Float16)a[1], (_Float16)a[2], (_Float16)a[3],
               (_Float16)c[0], (_Float16)c[1], (_Float16)c[2], (_Float16)c[3]};
    int h = c0 >> 6, dh = (c0 >> 5) & 1, g4 = (c0 >> 3) & 3;
    int k2 = r >> 4, l16 = r & 15;
    int lane = g4 * 16 + l16;
    size_t off = ((size_t)((bb * 16 + h) * 64 + kt)) * 2048 + (k2 * 2 + dh) * 512 + lane * 8;
    *(half8*)(KF + off) = o;
  } else if (bid < 3072) {
    int b3 = bid - 2048;
    int img = b3 >> 3;                     // 0..127
    int bb = img >> 6, kt = img & 63;
    int tix = ((b3 & 7) << 8) | tid;       // 0..2047
    int kq = tix >> 8;                     // 0..7
    int k2 = kq >> 2, g4 = kq & 3;
    int d0 = (tix & 255) << 2;             // 0..1020
    const float* src = v + ((size_t)(bb * SEQ + kt * 32 + k2 * 16 + g4 * 4)) * DM + d0;
    f32x4 m0 = *(const f32x4*)(src);
    f32x4 m1 = *(const f32x4*)(src + DM);
    f32x4 m2 = *(const f32x4*)(src + 2 * DM);
    f32x4 m3 = *(const f32x4*)(src + 3 * DM);
#pragma unroll
    for (int i = 0; i < 4; ++i) {
      int d = d0 + i;
      int l16 = d & 15, dt = (d >> 4) & 3, h = d >> 6;
      int lane = g4 * 16 + l16;
      half4 o = {(_Float16)m0[i], (_Float16)m1[i], (_Float16)m2[i], (_Float16)m3[i]};
      size_t off = ((size_t)((bb * 16 + h) * 64 + kt)) * 2048 + dt * 512 + lane * 8 + k2 * 4;
      *(half4*)(VF + off) = o;
    }
  } else {
    int b4 = bid - 3072;                   // 0..4095
    int job = b4 >> 5;                     // 0..127 = b*64+qblk32
    int bb = job >> 6, qblk = job & 63;
    int tix = ((b4 & 31) << 8) | tid;      // 0..8191
    int kt = tix >> 7;
    int rem = tix & 127;
    int g4 = rem & 3, l16 = (rem >> 2) & 15, qs = rem >> 6;
    int lane = g4 * 16 + l16;
    int qrow = qblk * 32 + qs * 16 + l16;
    size_t rowbase = ((size_t)(bb * SEQ + qrow)) * SEQ;
    u32x2 wds;
#pragma unroll
    for (int k2 = 0; k2 < 2; ++k2) {
      int kk = kt * 32 + k2 * 16 + g4 * 4;
      i32x4 dv = *(const i32x4*)(diff + rowbase + kk);
      i32x4 mv = *(const i32x4*)(mask + rowbase + kk);
      u32 bk[4];
#pragma unroll
      for (int r = 0; r < 4; ++r) bk[r] = mv[r] ? (u32)dv[r] : 20u;  // 20 = masked sentinel
      u32 pi01 = bk[0] * 21 + bk[1];
      u32 pi23 = bk[2] * 21 + bk[3];
      wds[k2] = pi01 | (pi23 << 16);
    }
    size_t off = ((size_t)job) * 65536 + (size_t)kt * 1024 + (size_t)lane * 16 + (size_t)qs * 8;
    *(u32x2*)(PB + off) = wds;
  }
}

__device__ __forceinline__ void gll16(const _Float16* g, _Float16* l) {
  __builtin_amdgcn_global_load_lds(
      (const __attribute__((address_space(1))) unsigned int*)g,
      (__attribute__((address_space(3))) unsigned int*)l, 16, 0, 0);
}

// packed-f16 silu; bias already in s (came through the MFMA C-operand in f32)
__device__ __forceinline__ half4 silu4nb(const f32x4& s) {
  h2v x01 = __builtin_bit_cast(h2v, __builtin_amdgcn_cvt_pkrtz(s[0], s[1]));
  h2v x23 = __builtin_bit_cast(h2v, __builtin_amdgcn_cvt_pkrtz(s[2], s[3]));
  const h2v NL2E = {(_Float16)-1.44269504f, (_Float16)-1.44269504f};
  const h2v ONE = {(_Float16)1.0f, (_Float16)1.0f};
  h2v m01 = x01 * NL2E, m23 = x23 * NL2E;
  h2v e01 = __builtin_bit_cast(h2v, h2exp2(__builtin_bit_cast(__half2, m01)));
  h2v e23 = __builtin_bit_cast(h2v, h2exp2(__builtin_bit_cast(__half2, m23)));
  h2v d01 = e01 + ONE, d23 = e23 + ONE;
  h2v y01 = x01 * __builtin_bit_cast(h2v, h2rcp(__builtin_bit_cast(__half2, d01)));
  h2v y23 = x23 * __builtin_bit_cast(h2v, h2rcp(__builtin_bit_cast(__half2, d23)));
  return (half4){y01[0], y01[1], y23[0], y23[1]};
}

struct BiasSet { f32x4 b[2][2]; };  // [qs][k2], f32 — feeds QK C-operand

// =================== main: R21 structure, SAFE register budget ===================
// R21's (512,8) forced VGPR 32 < ~52 live -> 1.2GB spill (R5's failure repeated). Same
// kernel at (512,4): cap 128, natural ~52-64, no spill; LDS 36.4KB x 4 blocks = 145KB
// fits 4 blocks/CU; 1024-block grid supplies up to 32 waves/CU and the HW packs what
// the VGPR file allows. This is the clean max-TLP test.
__global__ __launch_bounds__(512, 4) void pa_main(
    const _Float16* __restrict__ KF, const _Float16* __restrict__ VF,
    const unsigned char* __restrict__ PB, const float* __restrict__ q,
    const float* __restrict__ relbias, float* __restrict__ out) {
  __shared__ __align__(16) _Float16 ringK[8][2048];  // 32KB K ring (+ reduce scratch)
  __shared__ f32x2 tabF[441];                        // (rb[i], rb[j]) pair table

  const int tid = threadIdx.x, lane = tid & 63, wid = tid >> 6;  // wid 0..7
  const int qt = wid & 3, w2 = wid >> 2;   // k-quarter, qblk-within-block
  const int l16 = lane & 15, g4 = lane >> 4;
  const int xcd = blockIdx.x & 7;          // bid%8 = XCD
  const int i = blockIdx.x >> 3;           // 0..127 within XCD
  const int b = xcd >> 2;                  // XCD owns (b, 4-head group)
  const int hg = xcd & 3;
  const int h = hg * 4 + (i & 3);
  const int qgrp2 = i >> 2;                // 0..31
  const int qblk = qgrp2 * 2 + w2;         // 0..63
  const int qbase = qblk * 32;

  // build pair table
  for (int e = tid; e < 441; e += 512) {
    int bi = e / 21, bj = e - bi * 21;
    float vi = (bi < NB) ? relbias[bi * NH + h] : -30000.0f;
    float vj = (bj < NB) ? relbias[bj * NH + h] : -30000.0f;
    tabF[e] = (f32x2){vi, vj};
  }

  half8 qf[2][2];
#pragma unroll
  for (int qs = 0; qs < 2; ++qs)
#pragma unroll
    for (int dh = 0; dh < 2; ++dh) {
      const float* s = q + ((size_t)(b * SEQ + qbase + qs * 16 + l16)) * DM + h * 64 + dh * 32 + g4 * 8;
      f32x4 a = *(const f32x4*)s;
      f32x4 c = *(const f32x4*)(s + 4);
      qf[qs][dh] = {(_Float16)(a[0] * 0.125f), (_Float16)(a[1] * 0.125f),
                    (_Float16)(a[2] * 0.125f), (_Float16)(a[3] * 0.125f),
                    (_Float16)(c[0] * 0.125f), (_Float16)(c[1] * 0.125f),
                    (_Float16)(c[2] * 0.125f), (_Float16)(c[3] * 0.125f)};
    }

  f32x4 acc[2][4];
#pragma unroll
  for (int qs = 0; qs < 2; ++qs)
#pragma unroll
    for (int dt = 0; dt < 4; ++dt) acc[qs][dt] = (f32x4){0.f, 0.f, 0.f, 0.f};

  const _Float16* kfb = KF + ((size_t)((b * 16 + h) * 64)) * 2048 + lane * 8;
  const _Float16* vfb = VF + ((size_t)((b * 16 + h) * 64)) * 2048 + lane * 8;
  const unsigned char* pbb = PB + ((size_t)(b * 64 + qblk)) * 65536 + lane * 16;
  const int ch = w2 * 1024;                // this wave's half-tile chunk

  // quarter's 2 waves stage the tile's two 2KB halves (2 gll16 each)
#define STAGE(T)                                                            \
  do {                                                                      \
    gll16(kfb + (size_t)(T) * 2048 + ch, &ringK[(T) & 7][ch]);              \
    gll16(kfb + (size_t)(T) * 2048 + ch + 512, &ringK[(T) & 7][ch + 512]);  \
  } while (0)
#define CLMP(T) ((T) < 64 ? (T) : 63)

#define GATHER(BS, PQ)                                                 \
  do {                                                                 \
    _Pragma("unroll") for (int qs = 0; qs < 2; ++qs)                   \
      _Pragma("unroll") for (int k2 = 0; k2 < 2; ++k2) {               \
        u32 w = (u32)PQ[qs * 2 + k2];                                  \
        f32x2 p01 = tabF[w & 0xffffu];                                 \
        f32x2 p23 = tabF[w >> 16];                                     \
        BS.b[qs][k2] = (f32x4){p01[0], p01[1], p23[0], p23[1]};        \
      }                                                                \
  } while (0)

#define COMPUTE(T, BS)                                                                       \
  do {                                                                                       \
    int sl_ = (T) & 7;                                                                       \
    half8 vvr[4];                                                                            \
    _Pragma("unroll") for (int j = 0; j < 4; ++j)                                            \
      vvr[j] = *(const half8*)(vfb + (size_t)(T) * 2048 + j * 512);   /* VMEM / L1 */        \
    half8 kfr[4];                                                                            \
    _Pragma("unroll") for (int j = 0; j < 4; ++j)                                            \
      kfr[j] = *(const half8*)&ringK[sl_][j * 512 + lane * 8];        /* LDS pipe */         \
    f32x4 sa[2][2];                                                                          \
    _Pragma("unroll") for (int qs = 0; qs < 2; ++qs)                                         \
      _Pragma("unroll") for (int k2 = 0; k2 < 2; ++k2) {                                     \
        sa[qs][k2] = __builtin_amdgcn_mfma_f32_16x16x32_f16(kfr[k2 * 2 + 0], qf[qs][0],      \
                                                            BS.b[qs][k2], 0, 0, 0);          \
        sa[qs][k2] = __builtin_amdgcn_mfma_f32_16x16x32_f16(kfr[k2 * 2 + 1], qf[qs][1],      \
                                                            sa[qs][k2], 0, 0, 0);            \
      }                                                                                      \
    half8 pf8[2];                                                                            \
    _Pragma("unroll") for (int qs = 0; qs < 2; ++qs) {                                       \
      half4 p0 = silu4nb(sa[qs][0]);                                                         \
      half4 p1 = silu4nb(sa[qs][1]);                                                         \
      pf8[qs] = (half8){p0[0], p0[1], p0[2], p0[3], p1[0], p1[1], p1[2], p1[3]};             \
    }                                                                                        \
    _Pragma("unroll") for (int qs = 0; qs < 2; ++qs)                                         \
      _Pragma("unroll") for (int dt = 0; dt < 4; ++dt)                                       \
        acc[qs][dt] = __builtin_amdgcn_mfma_f32_16x16x32_f16(pf8[qs], vvr[dt],               \
                                                             acc[qs][dt], 0, 0, 0);          \
  } while (0)

  BiasSet bias;
  i32x4 pqCur, pqNext;

  // prologue: stage tile qt (slot qt); pq(qt) in flight
  STAGE(qt);
  pqCur = *(const i32x4*)(pbb + (size_t)qt * 1024);
  __syncthreads();                       // slots 0..3 staged

  for (int p = 0; p < 16; ++p) {
    const int T = 4 * p + qt;
    // stage T+4 into slot (T+4)&7 — freed by last phase's barrier
    if (T + 4 < 64) STAGE(T + 4);
    pqNext = *(const i32x4*)(pbb + (size_t)CLMP(T + 4) * 1024);
    __builtin_amdgcn_sched_barrier(0);
    GATHER(bias, pqCur);
    COMPUTE(T, bias);                    // covers stage(T+4) latency
    __syncthreads();                     // stage complete; slot (T)&7 released
    pqCur = pqNext;
  }
#undef STAGE
#undef CLMP
#undef GATHER
#undef COMPUTE

  // epilogue: 4-way k-quarter reduce via ring scratch (2 rounds), quarter 0 stores
  f32x4* red = (f32x4*)ringK;            // 2048 f32x4 = 32KB
#pragma unroll
  for (int qs = 0; qs < 2; ++qs) {
    __syncthreads();
    if (qt > 0) {
#pragma unroll
      for (int dt = 0; dt < 4; ++dt)
        red[((qt - 1) * 2 + w2) * 256 + lane * 4 + dt] = acc[qs][dt];
    }
    __syncthreads();
    if (qt == 0) {
#pragma unroll
      for (int dt = 0; dt < 4; ++dt) {
        f32x4 sum = acc[qs][dt];
#pragma unroll
        for (int qq = 1; qq < 4; ++qq)
          sum += red[((qq - 1) * 2 + w2) * 256 + lane * 4 + dt];
#pragma unroll
        for (int r = 0; r < 4; ++r) {
          int qrow = qbase + qs * 16 + g4 * 4 + r;
          int d = h * 64 + dt * 16 + l16;
          out[((size_t)(b * SEQ) + qrow) * DM + d] = sum[r];
        }
      }
    }
  }
}

extern "C" void kernel_launch(void* const* d_in, const int* in_sizes, int n_in,
                              void* d_out, int out_size, void* d_ws, size_t ws_size,
                              hipStream_t stream) {
  const float* v = (const float*)d_in[0];
  const float* k = (const float*)d_in[1];
  const float* q = (const float*)d_in[2];
  const int* mask = (const int*)d_in[3];
  const int* diff = (const int*)d_in[4];
  const float* relbias = (const float*)d_in[5];
  float* out = (float*)d_out;

  _Float16* KF = (_Float16*)d_ws;
  _Float16* VF = KF + KF_HALVES;
  unsigned char* PB = (unsigned char*)(VF + VF_HALVES);
  if (ws_size < (size_t)25165824) return;

  pa_prep<<<7168, 256, 0, stream>>>(v, k, diff, mask, KF, VF, PB);
  pa_main<<<1024, 512, 0, stream>>>(KF, VF, PB, q, relbias, out);
}

// Round 23
// 87.117 us; speedup vs baseline: 3.3864x; 1.0844x over previous
//
#include <hip/hip_runtime.h>
#include <hip/hip_fp16.h>
#include <cstdint>
#include <cstddef>

// ---- problem constants ----
#define SEQ 2048
#define DM 1024
#define NH 16
#define NB 20

typedef _Float16 half8 __attribute__((ext_vector_type(8)));
typedef _Float16 half4 __attribute__((ext_vector_type(4)));
typedef _Float16 h2v __attribute__((ext_vector_type(2)));
typedef float f32x4 __attribute__((ext_vector_type(4)));
typedef float f32x2 __attribute__((ext_vector_type(2)));
typedef int i32x4 __attribute__((ext_vector_type(4)));
typedef unsigned int u32;
typedef unsigned int u32x2 __attribute__((ext_vector_type(2)));

// ws layout (25,165,824 B total):
//  KF [2][16][64][2048] halves : per (b,h,kt): [k2][dh][lane][8]       (QK^T A-frags, 16x16x32)
//  VF [2][16][64][2048] halves : per (b,h,kt): [dt][lane][k2*4+r]      (PV B-frags, K=32 pi-order)
//  PB [2][64][65536] bytes     : per (b,qblk32): [kt][lane][qs][k2] u32 = pair01 | pair23<<16
//                                pair = bucket0*21+bucket1 (bucket 20 = masked sentinel)
#define KF_HALVES 4194304
#define VF_HALVES 4194304

// =================== prepass ===================
__global__ __launch_bounds__(256) void pa_prep(
    const float* __restrict__ v, const float* __restrict__ k,
    const int* __restrict__ diff, const int* __restrict__ mask,
    _Float16* __restrict__ KF, _Float16* __restrict__ VF,
    unsigned char* __restrict__ PB) {
  const int bid = blockIdx.x, tid = threadIdx.x;
  if (bid < 2048) {
    int img = bid >> 4;                    // 0..127 = b*64+kt
    int bb = img >> 6, kt = img & 63;
    int tix = ((bid & 15) << 8) | tid;     // 0..4095
    int r = tix >> 7;                      // row in tile 0..31 (= k2*16+l16)
    int c0 = (tix & 127) << 3;             // col 0..1016
    const float* src = k + ((size_t)(bb * SEQ + kt * 32 + r)) * DM + c0;
    f32x4 a = *(const f32x4*)src;
    f32x4 c = *(const f32x4*)(src + 4);
    half8 o = {(_Float16)a[0], (_Float16)a[1], (_Float16)a[2], (_Float16)a[3],
               (_Float16)c[0], (_Float16)c[1], (_Float16)c[2], (_Float16)c[3]};
    int h = c0 >> 6, dh = (c0 >> 5) & 1, g4 = (c0 >> 3) & 3;
    int k2 = r >> 4, l16 = r & 15;
    int lane = g4 * 16 + l16;
    size_t off = ((size_t)((bb * 16 + h) * 64 + kt)) * 2048 + (k2 * 2 + dh) * 512 + lane * 8;
    *(half8*)(KF + off) = o;
  } else if (bid < 3072) {
    int b3 = bid - 2048;
    int img = b3 >> 3;                     // 0..127
    int bb = img >> 6, kt = img & 63;
    int tix = ((b3 & 7) << 8) | tid;       // 0..2047
    int kq = tix >> 8;                     // 0..7
    int k2 = kq >> 2, g4 = kq & 3;
    int d0 = (tix & 255) << 2;             // 0..1020
    const float* src = v + ((size_t)(bb * SEQ + kt * 32 + k2 * 16 + g4 * 4)) * DM + d0;
    f32x4 m0 = *(const f32x4*)(src);
    f32x4 m1 = *(const f32x4*)(src + DM);
    f32x4 m2 = *(const f32x4*)(src + 2 * DM);
    f32x4 m3 = *(const f32x4*)(src + 3 * DM);
#pragma unroll
    for (int i = 0; i < 4; ++i) {
      int d = d0 + i;
      int l16 = d & 15, dt = (d >> 4) & 3, h = d >> 6;
      int lane = g4 * 16 + l16;
      half4 o = {(_Float16)m0[i], (_Float16)m1[i], (_Float16)m2[i], (_Float16)m3[i]};
      size_t off = ((size_t)((bb * 16 + h) * 64 + kt)) * 2048 + dt * 512 + lane * 8 + k2 * 4;
      *(half4*)(VF + off) = o;
    }
  } else {
    int b4 = bid - 3072;                   // 0..4095
    int job = b4 >> 5;                     // 0..127 = b*64+qblk32
    int bb = job >> 6, qblk = job & 63;
    int tix = ((b4 & 31) << 8) | tid;      // 0..8191
    int kt = tix >> 7;
    int rem = tix & 127;
    int g4 = rem & 3, l16 = (rem >> 2) & 15, qs = rem >> 6;
    int lane = g4 * 16 + l16;
    int qrow = qblk * 32 + qs * 16 + l16;
    size_t rowbase = ((size_t)(bb * SEQ + qrow)) * SEQ;
    u32x2 wds;
#pragma unroll
    for (int k2 = 0; k2 < 2; ++k2) {
      int kk = kt * 32 + k2 * 16 + g4 * 4;
      i32x4 dv = *(const i32x4*)(diff + rowbase + kk);
      i32x4 mv = *(const i32x4*)(mask + rowbase + kk);
      u32 bk[4];
#pragma unroll
      for (int r = 0; r < 4; ++r) bk[r] = mv[r] ? (u32)dv[r] : 20u;  // 20 = masked sentinel
      u32 pi01 = bk[0] * 21 + bk[1];
      u32 pi23 = bk[2] * 21 + bk[3];
      wds[k2] = pi01 | (pi23 << 16);
    }
    size_t off = ((size_t)job) * 65536 + (size_t)kt * 1024 + (size_t)lane * 16 + (size_t)qs * 8;
    *(u32x2*)(PB + off) = wds;
  }
}

__device__ __forceinline__ void gll16(const _Float16* g, _Float16* l) {
  __builtin_amdgcn_global_load_lds(
      (const __attribute__((address_space(1))) unsigned int*)g,
      (__attribute__((address_space(3))) unsigned int*)l, 16, 0, 0);
}

// packed-f16 silu; bias already in s (came through the MFMA C-operand in f32)
__device__ __forceinline__ half4 silu4nb(const f32x4& s) {
  h2v x01 = __builtin_bit_cast(h2v, __builtin_amdgcn_cvt_pkrtz(s[0], s[1]));
  h2v x23 = __builtin_bit_cast(h2v, __builtin_amdgcn_cvt_pkrtz(s[2], s[3]));
  const h2v NL2E = {(_Float16)-1.44269504f, (_Float16)-1.44269504f};
  const h2v ONE = {(_Float16)1.0f, (_Float16)1.0f};
  h2v m01 = x01 * NL2E, m23 = x23 * NL2E;
  h2v e01 = __builtin_bit_cast(h2v, h2exp2(__builtin_bit_cast(__half2, m01)));
  h2v e23 = __builtin_bit_cast(h2v, h2exp2(__builtin_bit_cast(__half2, m23)));
  h2v d01 = e01 + ONE, d23 = e23 + ONE;
  h2v y01 = x01 * __builtin_bit_cast(h2v, h2rcp(__builtin_bit_cast(__half2, d01)));
  h2v y23 = x23 * __builtin_bit_cast(h2v, h2rcp(__builtin_bit_cast(__half2, d23)));
  return (half4){y01[0], y01[1], y23[0], y23[1]};
}

struct BiasSet { f32x4 b[2][2]; };  // [qs][k2], f32 — feeds QK C-operand

// =================== main: R20 final (best measured: 87.5us total, 69.6us main) ===================
// 512-thr blocks (8 waves), 512 blocks. Waves split by k-parity sharing one K-ring;
// V VMEM-direct (4 waves same addrs -> L1); pair-table bias gather -> QK C-operand;
// full-k per block -> no memset/atomics (intra-block LDS reduce, group0 stores).
// Plateau declared after 13 structural falsifications: all pipes <50%, latency/issue-bound.
__global__ __launch_bounds__(512, 4) void pa_main(
    const _Float16* __restrict__ KF, const _Float16* __restrict__ VF,
    const unsigned char* __restrict__ PB, const float* __restrict__ q,
    const float* __restrict__ relbias, float* __restrict__ out) {
  __shared__ __align__(16) _Float16 ringK[4][2048];  // 16KB K ring (also reduce scratch)
  __shared__ f32x2 tabF[441];                        // (rb[i], rb[j]) pair table

  const int tid = threadIdx.x, lane = tid & 63, wid = tid >> 6;  // wid 0..7
  const int w4 = wid & 3, par = wid >> 2;                        // chunk, k-parity
  const int l16 = lane & 15, g4 = lane >> 4;
  const int xcd = blockIdx.x & 7;        // bid%8 = XCD
  const int i = blockIdx.x >> 3;         // 0..63 within XCD
  const int b = xcd >> 2;                // XCD owns (b, 4-head group)
  const int hg = xcd & 3;
  const int h = hg * 4 + (i & 3);
  const int qgrp = i >> 2;               // 0..15
  const int qblk = qgrp * 4 + w4;
  const int qbase = qblk * 32;

  // build pair table
  for (int e = tid; e < 441; e += 512) {
    int bi = e / 21, bj = e - bi * 21;
    float vi = (bi < NB) ? relbias[bi * NH + h] : -30000.0f;
    float vj = (bj < NB) ? relbias[bj * NH + h] : -30000.0f;
    tabF[e] = (f32x2){vi, vj};
  }

  half8 qf[2][2];
#pragma unroll
  for (int qs = 0; qs < 2; ++qs)
#pragma unroll
    for (int dh = 0; dh < 2; ++dh) {
      const float* s = q + ((size_t)(b * SEQ + qbase + qs * 16 + l16)) * DM + h * 64 + dh * 32 + g4 * 8;
      f32x4 a = *(const f32x4*)s;
      f32x4 c = *(const f32x4*)(s + 4);
      qf[qs][dh] = {(_Float16)(a[0] * 0.125f), (_Float16)(a[1] * 0.125f),
                    (_Float16)(a[2] * 0.125f), (_Float16)(a[3] * 0.125f),
                    (_Float16)(c[0] * 0.125f), (_Float16)(c[1] * 0.125f),
                    (_Float16)(c[2] * 0.125f), (_Float16)(c[3] * 0.125f)};
    }

  f32x4 acc[2][4];
#pragma unroll
  for (int qs = 0; qs < 2; ++qs)
#pragma unroll
    for (int dt = 0; dt < 4; ++dt) acc[qs][dt] = (f32x4){0.f, 0.f, 0.f, 0.f};

  const _Float16* kfb = KF + ((size_t)((b * 16 + h) * 64)) * 2048 + lane * 8;
  const _Float16* vfb = VF + ((size_t)((b * 16 + h) * 64)) * 2048 + lane * 8;
  const unsigned char* pbb = PB + ((size_t)(b * 64 + qblk)) * 65536 + lane * 16;
  const int c512 = w4 * 512;

#define STAGE(T) gll16(kfb + (size_t)(T) * 2048 + c512, &ringK[(T) & 3][c512])
#define CLMP(T) ((T) < 64 ? (T) : 63)

#define GATHER(BS, PQ)                                                 \
  do {                                                                 \
    _Pragma("unroll") for (int qs = 0; qs < 2; ++qs)                   \
      _Pragma("unroll") for (int k2 = 0; k2 < 2; ++k2) {               \
        u32 w = (u32)PQ[qs * 2 + k2];                                  \
        f32x2 p01 = tabF[w & 0xffffu];                                 \
        f32x2 p23 = tabF[w >> 16];                                     \
        BS.b[qs][k2] = (f32x4){p01[0], p01[1], p23[0], p23[1]};        \
      }                                                                \
  } while (0)

#define COMPUTE(T, BS)                                                                       \
  do {                                                                                       \
    int sl_ = (T) & 3;                                                                       \
    half8 vvr[4];                                                                            \
    _Pragma("unroll") for (int j = 0; j < 4; ++j)                                            \
      vvr[j] = *(const half8*)(vfb + (size_t)(T) * 2048 + j * 512);   /* VMEM / L1 */        \
    half8 kfr[4];                                                                            \
    _Pragma("unroll") for (int j = 0; j < 4; ++j)                                            \
      kfr[j] = *(const half8*)&ringK[sl_][j * 512 + lane * 8];        /* LDS pipe */         \
    f32x4 sa[2][2];                                                                          \
    _Pragma("unroll") for (int qs = 0; qs < 2; ++qs)                                         \
      _Pragma("unroll") for (int k2 = 0; k2 < 2; ++k2) {                                     \
        sa[qs][k2] = __builtin_amdgcn_mfma_f32_16x16x32_f16(kfr[k2 * 2 + 0], qf[qs][0],      \
                                                            BS.b[qs][k2], 0, 0, 0);          \
        sa[qs][k2] = __builtin_amdgcn_mfma_f32_16x16x32_f16(kfr[k2 * 2 + 1], qf[qs][1],      \
                                                            sa[qs][k2], 0, 0, 0);            \
      }                                                                                      \
    half8 pf8[2];                                                                            \
    _Pragma("unroll") for (int qs = 0; qs < 2; ++qs) {                                       \
      half4 p0 = silu4nb(sa[qs][0]);                                                         \
      half4 p1 = silu4nb(sa[qs][1]);                                                         \
      pf8[qs] = (half8){p0[0], p0[1], p0[2], p0[3], p1[0], p1[1], p1[2], p1[3]};             \
    }                                                                                        \
    _Pragma("unroll") for (int qs = 0; qs < 2; ++qs)                                         \
      _Pragma("unroll") for (int dt = 0; dt < 4; ++dt)                                       \
        acc[qs][dt] = __builtin_amdgcn_mfma_f32_16x16x32_f16(pf8[qs], vvr[dt],               \
                                                             acc[qs][dt], 0, 0, 0);          \
  } while (0)

  BiasSet bias;
  i32x4 pqCur, pqNext;

  // prologue: stage tiles 0..3 (wave stages chunk w4 of tiles par, par+2); pq(par) in flight
  STAGE(par);
  STAGE(par + 2);
  pqCur = *(const i32x4*)(pbb + (size_t)par * 1024);
  __syncthreads();                       // stages 0..3 complete

  for (int p = 0; p < 32; ++p) {
    const int T = 2 * p + par;           // this wave's tile
    pqNext = *(const i32x4*)(pbb + (size_t)CLMP(T + 2) * 1024);
    __builtin_amdgcn_sched_barrier(0);
    GATHER(bias, pqCur);
    COMPUTE(T, bias);
    __syncthreads();                     // all waves done reading slots 2p&3,(2p+1)&3
    if (T + 4 < 64) STAGE(T + 4);        // refill freed slot (T+4)&3 == T&3
    pqCur = pqNext;
    __syncthreads();                     // stages for tiles 2p+4,2p+5 complete before use
  }
#undef STAGE
#undef CLMP
#undef GATHER
#undef COMPUTE

  // epilogue: combine k-parity partials via LDS (2 rounds of 16KB), group0 stores
  f32x4* red = (f32x4*)ringK;
#pragma unroll
  for (int qs = 0; qs < 2; ++qs) {
    __syncthreads();
    if (par == 1) {
#pragma unroll
      for (int dt = 0; dt < 4; ++dt) red[(w4 * 64 + lane) * 4 + dt] = acc[qs][dt];
    }
    __syncthreads();
    if (par == 0) {
#pragma unroll
      for (int dt = 0; dt < 4; ++dt) {
        f32x4 sum = acc[qs][dt] + red[(w4 * 64 + lane) * 4 + dt];
#pragma unroll
        for (int r = 0; r < 4; ++r) {
          int qrow = qbase + qs * 16 + g4 * 4 + r;
          int d = h * 64 + dt * 16 + l16;
          out[((size_t)(b * SEQ) + qrow) * DM + d] = sum[r];
        }
      }
    }
  }
}

extern "C" void kernel_launch(void* const* d_in, const int* in_sizes, int n_in,
                              void* d_out, int out_size, void* d_ws, size_t ws_size,
                              hipStream_t stream) {
  const float* v = (const float*)d_in[0];
  const float* k = (const float*)d_in[1];
  const float* q = (const float*)d_in[2];
  const int* mask = (const int*)d_in[3];
  const int* diff = (const int*)d_in[4];
  const float* relbias = (const float*)d_in[5];
  float* out = (float*)d_out;

  _Float16* KF = (_Float16*)d_ws;
  _Float16* VF = KF + KF_HALVES;
  unsigned char* PB = (unsigned char*)(VF + VF_HALVES);
  if (ws_size < (size_t)25165824) return;

  pa_prep<<<7168, 256, 0, stream>>>(v, k, diff, mask, KF, VF, PB);
  pa_main<<<512, 512, 0, stream>>>(KF, VF, PB, q, relbias, out);
}